// Round 7
// baseline (391.391 us; speedup 1.0000x reference)
//
#include <hip/hip_runtime.h>
#include <hip/hip_cooperative_groups.h>
#include <cstdint>
#include <cstddef>

namespace cg = cooperative_groups;

// Problem constants (B, S, E, H, MAXLEN) = (2, 2048, 1024, 16, 2048)
constexpr int Sn = 2048;
constexpr int En = 1024;
constexpr int Bn = 2;
constexpr int Hn = 16;
constexpr int CHUNK = 32;          // 32-row chunks
constexpr int NCH = Sn / CHUNK;    // 64 chunks per batch
constexpr int Mtot = Bn * Sn;      // 4096
constexpr int GCH = Mtot / CHUNK;  // 128 global chunks

typedef __bf16 bf16x8 __attribute__((ext_vector_type(8)));
typedef float  f32x4  __attribute__((ext_vector_type(4)));

__device__ __forceinline__ unsigned short f2bf(float f) {
    union { float f; uint32_t u; } v; v.f = f;
    const uint32_t u = v.u;
    return (unsigned short)((u + 0x7fffu + ((u >> 16) & 1u)) >> 16);  // RNE
}
__device__ __forceinline__ float bf2f(unsigned short s) {
    union { uint32_t u; float f; } v; v.u = (uint32_t)s << 16; return v.f;
}

// ---------------------------------------------------------------------------
// Fused fp32 -> bf16 cast of x (XN) and Wv (WN) in one launch.
// [R15: in-GEMM fp32 staging cost +16 µs. Separate cast wins.]
// ---------------------------------------------------------------------------
constexpr int XN = Bn * Sn * En;   // 4194304
constexpr int WN = En * En;        // 1048576

__global__ __launch_bounds__(256)
void cast2(const float* __restrict__ x, const float* __restrict__ Wv,
           unsigned short* __restrict__ xb, unsigned short* __restrict__ Wvb)
{
    const int i = (blockIdx.x * 256 + threadIdx.x) * 4;
    const float* src; unsigned short* dst; int off;
    if (i < XN) { src = x;  dst = xb;  off = i; }
    else        { src = Wv; dst = Wvb; off = i - XN; }
    const float4 v = *(const float4*)(src + off);
    ushort4 o;
    o.x = f2bf(v.x); o.y = f2bf(v.y); o.z = f2bf(v.z); o.w = f2bf(v.w);
    *(ushort4*)(dst + off) = o;
}

// ---------------------------------------------------------------------------
// GEMM body (device fn) — R6's verified 128x128 / 8-wave / BK=64 structure,
// verbatim. C[m,n] = sum_k A[m,k]*W[n,k] + bias[n].
// [Session counters: this family is latency/overhead-bound at this shape —
// MfmaUtil ~6%, all pipes idle; tile axis exhausted (64^2 worse, 128x64 ==
// 128x128); prefetch depth neutral. ~28-35 µs of content per GEMM.]
// LDS chunk = 16 rows x 32 k in fragment order, lane l -> slot l*16 B
// (conflict-free b128). XCD swizzle on id=0..255.
// ---------------------------------------------------------------------------
#define LOAD4(k0, r0, r1, r2, r3)                    \
    r0 = *(const uint4*)(gA0 + (k0));                \
    r1 = *(const uint4*)(gA0 + (k0) + 32);           \
    r2 = *(const uint4*)(gB0 + (k0));                \
    r3 = *(const uint4*)(gB0 + (k0) + 32);

#define STORE4(r0, r1, r2, r3)                       \
    *lA0 = r0; *lA1 = r1;                            \
    *lB0 = r2; *lB1 = r3;

#define COMPUTE()                                                                              \
    {                                                                                          \
        bf16x8 af[4][2], bfr[2][2];                                                            \
        _Pragma("unroll")                                                                      \
        for (int i = 0; i < 4; ++i)                                                            \
            _Pragma("unroll")                                                                  \
            for (int kh = 0; kh < 2; ++kh)                                                     \
                af[i][kh] = *(const bf16x8*)&As[((wr * 4 + i) * 2 + kh) * 512 + lane * 8];      \
        _Pragma("unroll")                                                                      \
        for (int j = 0; j < 2; ++j)                                                            \
            _Pragma("unroll")                                                                  \
            for (int kh = 0; kh < 2; ++kh)                                                     \
                bfr[j][kh] = *(const bf16x8*)&Bs[((wc * 2 + j) * 2 + kh) * 512 + lane * 8];     \
        _Pragma("unroll")                                                                      \
        for (int kh = 0; kh < 2; ++kh)                                                         \
            _Pragma("unroll")                                                                  \
            for (int i = 0; i < 4; ++i)                                                        \
                _Pragma("unroll")                                                              \
                for (int j = 0; j < 2; ++j)                                                    \
                    acc[i][j] = __builtin_amdgcn_mfma_f32_16x16x32_bf16(af[i][kh], bfr[j][kh], \
                                                                        acc[i][j], 0, 0, 0);   \
    }

template<bool APPLY_MASK, bool OUT_BF16, bool FUSE_CSUM>
__device__ __forceinline__
void gemm_body(unsigned short* As, unsigned short* Bs,
               const unsigned short* __restrict__ A, const unsigned short* __restrict__ Bw,
               const float* __restrict__ bias, const int* __restrict__ mask,
               void* __restrict__ Cv, float* __restrict__ csum,
               int id, int tid)
{
    const int lane = tid & 63;
    const int wv   = tid >> 6;      // wave 0..7
    const int wr   = wv >> 2;       // wave row (0..1) -> M half
    const int wc   = wv & 3;        // wave col (0..3) -> N quarter
    // XCD-aware swizzle (id 0..255, bijective).
    const int xcd  = id & 7;
    const int slot = id >> 3;       // 0..31
    const int by   = xcd * 4 + (slot >> 3);   // 0..31
    const int bx   = slot & 7;                // 0..7
    const int bm   = by * 128;
    const int bn   = bx * 128;
    const int m16  = lane & 15;
    const int kq   = lane >> 4;     // k-quarter (staging) / row-quad (C/D)

    f32x4 acc[4][2] = {};

    // Wave wv stages A row-group wv and B row-group wv (16 rows each).
    const unsigned short* gA0 = A  + (size_t)(bm + 16 * wv + m16) * En + kq * 8;
    const unsigned short* gB0 = Bw + (size_t)(bn + 16 * wv + m16) * En + kq * 8;
    uint4* lA0 = (uint4*)&As[(wv * 2 + 0) * 512 + lane * 8];
    uint4* lA1 = (uint4*)&As[(wv * 2 + 1) * 512 + lane * 8];
    uint4* lB0 = (uint4*)&Bs[(wv * 2 + 0) * 512 + lane * 8];
    uint4* lB1 = (uint4*)&Bs[(wv * 2 + 1) * 512 + lane * 8];

    // 8 individually named staging registers (arrays spill — R6 lesson).
    uint4 p0, p1, p2, p3;
    uint4 q0, q1, q2, q3;

    LOAD4(0, p0, p1, p2, p3);
    // K=1024, BK=64 -> 16 K-steps, 2x unrolled (alternating reg sets).
#pragma unroll 1
    for (int it = 0; it < 8; ++it) {
        const int kbase = it * 128;
        __syncthreads();                        // prev compute's LDS reads done
        STORE4(p0, p1, p2, p3);                 // waits vmcnt for p (1 step old)
        __syncthreads();                        // writes visible
        LOAD4(kbase + 64, q0, q1, q2, q3);      // in flight across MFMAs
        COMPUTE();

        __syncthreads();
        STORE4(q0, q1, q2, q3);
        __syncthreads();
        if (it < 7) { LOAD4(kbase + 128, p0, p1, p2, p3); }
        COMPUTE();
    }

    // Epilogue. C/D layout: col = lane&15, row = (lane>>4)*4 + reg.
    float colsum[2][2] = {{0.0f, 0.0f}, {0.0f, 0.0f}};
#pragma unroll
    for (int i = 0; i < 4; ++i) {
        const int r0_ = bm + wr * 64 + i * 16 + kq * 4;
#pragma unroll
        for (int j = 0; j < 2; ++j) {
            const int c0 = bn + wc * 32 + j * 16 + m16;
            const float bcol = bias[c0];
#pragma unroll
            for (int r = 0; r < 4; ++r) {
                const int row = r0_ + r;
                float val = acc[i][j][r] + bcol;
                if (APPLY_MASK) val = (mask[row] == 0) ? 0.0f : val;
                if (FUSE_CSUM) colsum[i >> 1][j] += val;
                if (OUT_BF16)
                    ((unsigned short*)Cv)[(size_t)row * En + c0] = f2bf(val);
                else
                    ((float*)Cv)[(size_t)row * En + c0] = val;
            }
        }
    }

    if (FUSE_CSUM) {
        // Wave wr's 64 rows = global chunks {4*by + 2*wr, +1} (CHUNK=32).
        const int gc0 = 4 * by + 2 * wr;
#pragma unroll
        for (int g = 0; g < 2; ++g)
#pragma unroll
            for (int j = 0; j < 2; ++j) {
                float s = colsum[g][j];
                s += __shfl_xor(s, 16, 64);
                s += __shfl_xor(s, 32, 64);
                if (kq == 0)
                    csum[(size_t)(gc0 + g) * En + bn + wc * 32 + j * 16 + m16] = s;
            }
    }
}

// ---------------------------------------------------------------------------
// fused (R20): ONE cooperative kernel = gemm1 -> prescan -> combine -> gemm2.
// [Cross-round accounting: ~35-50 µs of the 121 µs controllable budget is
// inter-dispatch overhead (content models: gemm ~30 each, combine ~5, cast
// ~5). 4 dispatches -> 2. grid.sync() between phases; 256 blocks x 512 thr
// co-resident at 1 block/CU (32 KB LDS, VGPR ~90 < 128).]
// Phase A: gemm1 (mask+bf16+csum) — R6 body verbatim.
// Phase B: blocks 0..3 (2048 threads) compute the per-(b,e) exclusive
//          chunk-prefix ONCE (was recomputed by all 512 combine blocks).
// Phase C: combine minus scan; 2 virtual 256-thr blocks per real block;
//          LDS tiles overlay As (half 0) and Bs (half 1); Wo cast slice.
// Phase D: gemm2 (plain fp32 out) — R6 body verbatim.
// ---------------------------------------------------------------------------
__global__ __launch_bounds__(512, 2)
void fused(const unsigned short* __restrict__ xb, const unsigned short* __restrict__ Wvb,
           const float* __restrict__ bv, const int* __restrict__ mask,
           unsigned short* __restrict__ vmb, float* __restrict__ csum,
           float* __restrict__ prefexc, float* __restrict__ Tbuf,
           const float* __restrict__ hier, const float* __restrict__ Wo,
           unsigned short* __restrict__ Wob, unsigned short* __restrict__ opreb,
           const float* __restrict__ bo, float* __restrict__ out)
{
    __shared__ __align__(16) unsigned short As[128 * 64];  // 16 KB
    __shared__ __align__(16) unsigned short Bs[128 * 64];  // 16 KB

    const int tid = threadIdx.x;
    const int rb  = blockIdx.y * 8 + blockIdx.x;   // 0..255

    // ---- Phase A: vm = mask ? (x @ Wv.T + bv) : 0 (bf16) + chunk col sums
    gemm_body<true, true, true>(As, Bs, xb, Wvb, bv, mask, vmb, csum, rb, tid);

    __threadfence();
    cg::this_grid().sync();

    // ---- Phase B: exclusive chunk-prefix scan, once per (b,e) column.
    if (rb < 4) {
        const int t = rb * 512 + tid;          // 0..2047
        const int b = t >> 10, e = t & 1023;
        const float* cp = csum + (size_t)b * NCH * En + e;
        float* pp = prefexc + (size_t)b * NCH * En + e;
        float run = 0.0f;
#pragma unroll 8
        for (int c2 = 0; c2 < NCH; ++c2) {
            const float v = cp[(size_t)c2 * En];
            pp[(size_t)c2 * En] = run;
            run += v;
        }
        Tbuf[b * En + e] = run;
    }

    __threadfence();
    cg::this_grid().sync();

    // ---- Phase C: weighted combine -> opre (bf16) + Wo cast slice.
    {
        const int half = tid >> 8;             // 0/1: two virtual blocks
        const int t8   = tid & 255;
        const int vb   = rb * 2 + half;        // 0..511 (old grid (4,64,2))
        const int bx   = vb & 3;
        const int cc   = (vb >> 2) & 63;       // chunk within batch
        const int b    = vb >> 8;
        const int ec0  = bx * 256;
        unsigned short* tile = half ? Bs : As;   // 16 KB each, exact fit

        // Stage 32x256 vm tile -> LDS: 4 passes x (8 rows x 32 lanes x 16 B).
        {
            const int lane16 = t8 & 31;
            const int rbase  = t8 >> 5;
            const size_t g0 = ((size_t)b * Sn + cc * CHUNK) * En + ec0 + lane16 * 8;
#pragma unroll
            for (int r4 = 0; r4 < 4; ++r4) {
                const int row = r4 * 8 + rbase;
                *(uint4*)&tile[row * 256 + lane16 * 8] =
                    *(const uint4*)(vmb + g0 + (size_t)row * En);
            }
        }

        // Wo cast slice: 512 vb x 256 thr x 8 elems = 1M elements.
        {
            const int base = vb * 2048 + t8 * 4;
#pragma unroll
            for (int hf = 0; hf < 2; ++hf) {
                const int off = base + hf * 1024;
                const float4 v = *(const float4*)(Wo + off);
                ushort4 o;
                o.x = f2bf(v.x); o.y = f2bf(v.y); o.z = f2bf(v.z); o.w = f2bf(v.w);
                *(ushort4*)(Wob + off) = o;
            }
        }

        const int e = ec0 + t8;
        const int h = e >> 6;   // dh = 64
        const float w0 = hier[((size_t)b * Hn + h) * 3 + 0];
        const float w1 = hier[((size_t)b * Hn + h) * 3 + 1] * 0.5f;
        const float w2 = hier[((size_t)b * Hn + h) * 3 + 2] * 0.25f;

        // Prefix and total from Phase B (2 loads — scan loop eliminated).
        float run = prefexc[(size_t)(b * NCH + cc) * En + e];
        const float T = Tbuf[b * En + e];

        __syncthreads();   // vm tiles visible (both halves)

        float prev = 0.0f;
        const size_t base = ((size_t)b * Sn + cc * CHUNK) * En + e;

#pragma unroll
        for (int t = 0; t < CHUNK; ++t) {
            const int i = cc * CHUNK + t;
            const float cur = bf2f(tile[t * 256 + t8]);
            float num, Z;
            if (i & 1) {
                num = w2 * (run - prev) + w1 * prev + w0 * (T - run);
                Z = (float)(i - 1) * w2 + w1 + (float)(Sn - i) * w0 + 1e-8f;
            } else {
                num = w2 * run + w0 * (T - run);
                Z = (float)i * w2 + (float)(Sn - i) * w0 + 1e-8f;
            }
            opreb[base + (size_t)t * En] = f2bf(num / Z);
            run += cur;
            prev = cur;
        }
    }

    __threadfence();
    cg::this_grid().sync();

    // ---- Phase D: out = opre @ Wo.T + bo (fp32 out)
    gemm_body<false, false, false>(As, Bs, opreb, Wob, bo, nullptr, out, nullptr, rb, tid);
}

// ---------------------------------------------------------------------------
extern "C" void kernel_launch(void* const* d_in, const int* in_sizes, int n_in,
                              void* d_out, int out_size, void* d_ws, size_t ws_size,
                              hipStream_t stream)
{
    // 0:x 1:attention_mask 2:level_indices 3:Wq 4:bq 5:Wk 6:bk 7:Wv 8:bv 9:hier 10:Wo 11:bo
    const float* x    = (const float*)d_in[0];
    const int*   mask = (const int*)d_in[1];
    const float* Wv   = (const float*)d_in[7];
    const float* bv   = (const float*)d_in[8];
    const float* hier = (const float*)d_in[9];
    const float* Wo   = (const float*)d_in[10];
    const float* bo   = (const float*)d_in[11];
    float* out = (float*)d_out;

    char* ws = (char*)d_ws;
    unsigned short* xb    = (unsigned short*)ws;  ws += (size_t)Mtot * En * 2;   // 8 MB
    unsigned short* Wvb   = (unsigned short*)ws;  ws += (size_t)En * En * 2;     // 2 MB
    unsigned short* Wob   = (unsigned short*)ws;  ws += (size_t)En * En * 2;     // 2 MB
    unsigned short* vmb   = (unsigned short*)ws;  ws += (size_t)Mtot * En * 2;   // 8 MB
    float*          csum  = (float*)ws;           ws += (size_t)GCH * En * 4;    // 512 KB
    unsigned short* opreb = (unsigned short*)ws;  ws += (size_t)Mtot * En * 2;   // 8 MB
    float*          pref  = (float*)ws;           ws += (size_t)GCH * En * 4;    // 512 KB
    float*          Tbuf  = (float*)ws;           ws += (size_t)Bn * En * 4;     // 8 KB

    // 1) Casts to bf16: x + Wv (Wo is cast inside fused phase C, pre-gemm2)
    cast2<<<dim3((XN + WN) / 1024), dim3(256), 0, stream>>>(x, Wv, xb, Wvb);

    // 2) gemm1 -> prescan -> combine -> gemm2, one cooperative launch.
    void* args[] = {
        (void*)&xb, (void*)&Wvb, (void*)&bv, (void*)&mask,
        (void*)&vmb, (void*)&csum, (void*)&pref, (void*)&Tbuf,
        (void*)&hier, (void*)&Wo, (void*)&Wob, (void*)&opreb,
        (void*)&bo, (void*)&out
    };
    hipLaunchCooperativeKernel((const void*)fused, dim3(8, 32), dim3(512),
                               args, 0, stream);
}

// Round 8
// 163.062 us; speedup vs baseline: 2.4003x; 2.4003x over previous
//
#include <hip/hip_runtime.h>
#include <cstdint>
#include <cstddef>

// Problem constants (B, S, E, H, MAXLEN) = (2, 2048, 1024, 16, 2048)
constexpr int Sn = 2048;
constexpr int En = 1024;
constexpr int Bn = 2;
constexpr int Hn = 16;
constexpr int CHUNK = 32;          // 32-row chunks (2 per wave tile)
constexpr int NCH = Sn / CHUNK;    // 64 chunks per batch
constexpr int Mtot = Bn * Sn;      // 4096
constexpr int GCH = Mtot / CHUNK;  // 128 global chunks

typedef __bf16 bf16x8 __attribute__((ext_vector_type(8)));
typedef float  f32x4  __attribute__((ext_vector_type(4)));

__device__ __forceinline__ unsigned short f2bf(float f) {
    union { float f; uint32_t u; } v; v.f = f;
    const uint32_t u = v.u;
    return (unsigned short)((u + 0x7fffu + ((u >> 16) & 1u)) >> 16);  // RNE
}
__device__ __forceinline__ float bf2f(unsigned short s) {
    union { uint32_t u; float f; } v; v.u = (uint32_t)s << 16; return v.f;
}

// ---------------------------------------------------------------------------
// Fused fp32 -> bf16 cast of x (XN) and Wv (WN) in one launch.
// [R15: in-GEMM fp32 staging cost +16 µs. Separate cast wins.
//  R7: cooperative-kernel fusion cost +200 µs of grid.sync stall (XCD L2
//  flush per device fence). 4 separate dispatches is the right structure.]
// ---------------------------------------------------------------------------
constexpr int XN = Bn * Sn * En;   // 4194304
constexpr int WN = En * En;        // 1048576

__global__ __launch_bounds__(256)
void cast2(const float* __restrict__ x, const float* __restrict__ Wv,
           unsigned short* __restrict__ xb, unsigned short* __restrict__ Wvb)
{
    const int i = (blockIdx.x * 256 + threadIdx.x) * 4;
    const float* src; unsigned short* dst; int off;
    if (i < XN) { src = x;  dst = xb;  off = i; }
    else        { src = Wv; dst = Wvb; off = i - XN; }
    const float4 v = *(const float4*)(src + off);
    ushort4 o;
    o.x = f2bf(v.x); o.y = f2bf(v.y); o.z = f2bf(v.z); o.w = f2bf(v.w);
    *(ushort4*)(dst + off) = o;
}

// ---------------------------------------------------------------------------
// bf16 MFMA GEMM (NT) — R21: R13 structure + LDS DOUBLE-BUFFER (one barrier
// per K-step instead of two). C[m,n] = sum_k A[m,k]*W[n,k] + bias[n].
// Tile 128(M) x 64(N), BK=64, 256 threads = 4 waves in 2x2, wave tile 64x32.
// [Falsified axes: prefetch depth (R1 null), fp32 staging (R2 -16µs), tile
// 64² (R5 -13µs) and 128² (R6 null), coop fusion (R7 -200µs). Remaining:
// barrier count. Single-buffer forced sync;STORE;sync per step = 32
// barriers/kernel. Dbuf: step t reads buf[t&1], stores tile t+1 into
// buf[(t+1)&1] AFTER compute -> 17 barriers, and each reg-set's vmcnt wait
// gains a compute phase + barrier of cover. Private-VGPR prefetch loads are
// NOT drained at __syncthreads (lgkmcnt-only drain) — session-verified.]
// LDS: 2 x (16 KB As + 8 KB Bs) = 48 KB -> still 2 blocks/CU by LDS.
// Chunk = 16 rows x 32 k in fragment order, lane l -> slot l*16 B
// (conflict-free b128). XCD swizzle: xcd = id&7 owns 4 contiguous
// row-blocks (A 1 MB + B 2 MB < 4 MB per-XCD L2).
// FUSE_CSUM: wave wr's 64 rows = global chunks {4*by+2*wr, +1}; butterfly
// over kq, unique writer kq==0.
// ---------------------------------------------------------------------------
#define LOAD6(k0, r0, r1, r2, r3, r4, r5)            \
    r0 = *(const uint4*)(gA0 + (k0));                \
    r1 = *(const uint4*)(gA0 + (k0) + 32);           \
    r2 = *(const uint4*)(gA1 + (k0));                \
    r3 = *(const uint4*)(gA1 + (k0) + 32);           \
    r4 = *(const uint4*)(gB0 + (k0));                \
    r5 = *(const uint4*)(gB0 + (k0) + 32);

#define STORE6B(B, r0, r1, r2, r3, r4, r5)                       \
    *(uint4*)&As[B][(rg0 * 2 + 0) * 512 + lane * 8] = r0;        \
    *(uint4*)&As[B][(rg0 * 2 + 1) * 512 + lane * 8] = r1;        \
    *(uint4*)&As[B][(rg1 * 2 + 0) * 512 + lane * 8] = r2;        \
    *(uint4*)&As[B][(rg1 * 2 + 1) * 512 + lane * 8] = r3;        \
    *(uint4*)&Bs[B][(wv  * 2 + 0) * 512 + lane * 8] = r4;        \
    *(uint4*)&Bs[B][(wv  * 2 + 1) * 512 + lane * 8] = r5;

#define COMPUTEB(B)                                                                            \
    {                                                                                          \
        bf16x8 af[4][2], bfr[2][2];                                                            \
        _Pragma("unroll")                                                                      \
        for (int i = 0; i < 4; ++i)                                                            \
            _Pragma("unroll")                                                                  \
            for (int kh = 0; kh < 2; ++kh)                                                     \
                af[i][kh] = *(const bf16x8*)&As[B][((wr * 4 + i) * 2 + kh) * 512 + lane * 8];   \
        _Pragma("unroll")                                                                      \
        for (int j = 0; j < 2; ++j)                                                            \
            _Pragma("unroll")                                                                  \
            for (int kh = 0; kh < 2; ++kh)                                                     \
                bfr[j][kh] = *(const bf16x8*)&Bs[B][((wc * 2 + j) * 2 + kh) * 512 + lane * 8]; \
        _Pragma("unroll")                                                                      \
        for (int kh = 0; kh < 2; ++kh)                                                         \
            _Pragma("unroll")                                                                  \
            for (int i = 0; i < 4; ++i)                                                        \
                _Pragma("unroll")                                                              \
                for (int j = 0; j < 2; ++j)                                                    \
                    acc[i][j] = __builtin_amdgcn_mfma_f32_16x16x32_bf16(af[i][kh], bfr[j][kh], \
                                                                        acc[i][j], 0, 0, 0);   \
    }

template<bool APPLY_MASK, bool OUT_BF16, bool FUSE_CSUM>
__global__ __launch_bounds__(256)
void gemm_pipe(const unsigned short* __restrict__ A, const unsigned short* __restrict__ Bw,
               const float* __restrict__ bias, const int* __restrict__ mask,
               void* __restrict__ Cv, float* __restrict__ csum)
{
    __shared__ __align__(16) unsigned short As[2][128 * 64];  // 2 x 16 KB
    __shared__ __align__(16) unsigned short Bs[2][64 * 64];   // 2 x 8 KB

    const int tid  = threadIdx.x;
    const int lane = tid & 63;
    const int wv   = tid >> 6;      // wave 0..3
    const int wr   = wv >> 1;       // wave row (0..1) -> M
    const int wc   = wv & 1;        // wave col (0..1) -> N
    // XCD-aware swizzle (grid (16, 32)).
    const int id   = blockIdx.y * 16 + blockIdx.x;
    const int xcd  = id & 7;
    const int slot = id >> 3;
    const int by   = xcd * 4 + (slot >> 4);
    const int bx   = slot & 15;
    const int bm   = by * 128;
    const int bn   = bx * 64;
    const int m16  = lane & 15;
    const int kq   = lane >> 4;     // k-quarter (staging) / row-quad (C/D)

    f32x4 acc[4][2] = {};

    const int rg0 = 2 * wv, rg1 = 2 * wv + 1;
    const unsigned short* gA0 = A  + (size_t)(bm + 16 * rg0 + m16) * En + kq * 8;
    const unsigned short* gA1 = A  + (size_t)(bm + 16 * rg1 + m16) * En + kq * 8;
    const unsigned short* gB0 = Bw + (size_t)(bn + 16 * wv  + m16) * En + kq * 8;

    // 12 individually named staging registers (arrays spill — R6 lesson).
    uint4 p0, p1, p2, p3, p4, p5;
    uint4 q0, q1, q2, q3, q4, q5;

    // Pipeline: step t reads buf[t&1]; stores for tile t+1 happen at step t
    // AFTER compute. K=1024, BK=64 -> 16 K-steps.
    LOAD6(0,  p0, p1, p2, p3, p4, p5);          // tile 0
    STORE6B(0, p0, p1, p2, p3, p4, p5);         // waits vmcnt(0) once
    LOAD6(64, q0, q1, q2, q3, q4, q5);          // tile 1
    __syncthreads();                            // buf0 ready

#pragma unroll 1
    for (int it = 0; it < 7; ++it) {            // steps 0..13
        const int kb = it * 128;
        // even step 2it: read buf0
        LOAD6(kb + 128, p0, p1, p2, p3, p4, p5);     // tile 2it+2
        COMPUTEB(0);
        STORE6B(1, q0, q1, q2, q3, q4, q5);          // tile 2it+1 (cover: 1 phase)
        __syncthreads();
        // odd step 2it+1: read buf1
        LOAD6(kb + 192, q0, q1, q2, q3, q4, q5);     // tile 2it+3
        COMPUTEB(1);
        STORE6B(0, p0, p1, p2, p3, p4, p5);          // tile 2it+2
        __syncthreads();
    }
    // step 14: read buf0 (tile 14); stage tile 15
    COMPUTEB(0);
    STORE6B(1, q0, q1, q2, q3, q4, q5);
    __syncthreads();
    // step 15: read buf1 (tile 15)
    COMPUTEB(1);

    // Epilogue. C/D layout: col = lane&15, row = (lane>>4)*4 + reg.
    // colsum[g][j]: g = 32-row half of the wave tile, j = 16-col group.
    float colsum[2][2] = {{0.0f, 0.0f}, {0.0f, 0.0f}};
#pragma unroll
    for (int i = 0; i < 4; ++i) {
        const int r0_ = bm + wr * 64 + i * 16 + kq * 4;
#pragma unroll
        for (int j = 0; j < 2; ++j) {
            const int c0 = bn + wc * 32 + j * 16 + m16;
            const float bcol = bias[c0];
#pragma unroll
            for (int r = 0; r < 4; ++r) {
                const int row = r0_ + r;
                float val = acc[i][j][r] + bcol;
                if (APPLY_MASK) val = (mask[row] == 0) ? 0.0f : val;
                if (FUSE_CSUM) colsum[i >> 1][j] += val;
                if (OUT_BF16)
                    ((unsigned short*)Cv)[(size_t)row * En + c0] = f2bf(val);
                else
                    ((float*)Cv)[(size_t)row * En + c0] = val;
            }
        }
    }

    if (FUSE_CSUM) {
        // Wave wr's 64 rows = global chunks {4*by + 2*wr, +1} (CHUNK=32).
        const int gc0 = 4 * by + 2 * wr;
#pragma unroll
        for (int g = 0; g < 2; ++g)
#pragma unroll
            for (int j = 0; j < 2; ++j) {
                float s = colsum[g][j];
                s += __shfl_xor(s, 16, 64);
                s += __shfl_xor(s, 32, 64);
                if (kq == 0)
                    csum[(size_t)(gc0 + g) * En + bn + wc * 32 + j * 16 + m16] = s;
            }
    }
}

// ---------------------------------------------------------------------------
// combine (R16 structure): Wo cast slice + LDS-staged vm tile + pipelined
// csum scan + weighted combine -> opre (bf16).
//   out_pre[b,i,e] = (w2*Pref[i&~1] + (i odd)*w1*vm[i-1] + w0*(T-Pref[i]))/Z
//   Z = (i&~1)*w2 + (i odd)*w1 + (S-i)*w0 + 1e-8
// Grid (4, 64, 2) = 512 blocks = 2/CU. Chunk starts even, so odd-i prev is
// always in-chunk. gemm2 (reads Wob) launches after us.
// ---------------------------------------------------------------------------
__global__ __launch_bounds__(256)
void combine(const unsigned short* __restrict__ vm, const float* __restrict__ csum,
             const float* __restrict__ hier, const float* __restrict__ Wo,
             unsigned short* __restrict__ Wob, unsigned short* __restrict__ opre)
{
    __shared__ __align__(16) unsigned short tile[CHUNK * 256];  // 16 KB

    const int tid = threadIdx.x;
    const int ec0 = blockIdx.x * 256;
    const int c   = blockIdx.y;     // chunk within batch, 0..63
    const int b   = blockIdx.z;

    // --- Stage 32x256 vm tile -> LDS: 4 passes x (8 rows x 32 lanes x 16 B).
    {
        const int lane16 = tid & 31;          // 16B segment within a row
        const int rbase  = tid >> 5;          // 0..7
        const size_t g0 = ((size_t)b * Sn + c * CHUNK) * En + ec0 + lane16 * 8;
#pragma unroll
        for (int r4 = 0; r4 < 4; ++r4) {
            const int row = r4 * 8 + rbase;
            *(uint4*)&tile[row * 256 + lane16 * 8] =
                *(const uint4*)(vm + g0 + (size_t)row * En);
        }
    }

    // --- Wo cast slice: 512 blocks x 256 threads x 8 elems = 1M elements.
    {
        const int fid = (blockIdx.z * 64 + blockIdx.y) * 4 + blockIdx.x;  // 0..511
        const int base = fid * 2048 + tid * 4;
#pragma unroll
        for (int half = 0; half < 2; ++half) {
            const int off = base + half * 1024;
            const float4 v = *(const float4*)(Wo + off);
            ushort4 o;
            o.x = f2bf(v.x); o.y = f2bf(v.y); o.z = f2bf(v.z); o.w = f2bf(v.w);
            *(ushort4*)(Wob + off) = o;
        }
    }

    const int e = ec0 + tid;
    const int h = e >> 6;   // dh = 64
    const float w0 = hier[((size_t)b * Hn + h) * 3 + 0];
    const float w1 = hier[((size_t)b * Hn + h) * 3 + 1] * 0.5f;
    const float w2 = hier[((size_t)b * Hn + h) * 3 + 2] * 0.25f;

    // --- Exclusive scan over this batch's 64 chunk sums (coalesced, x16
    //     unrolled so loads cluster; c is block-uniform -> branchless add).
    float run = 0.0f, T = 0.0f;
    {
        const float* cp = csum + (size_t)b * NCH * En + e;
#pragma unroll 16
        for (int c2 = 0; c2 < NCH; ++c2) {
            const float v = cp[(size_t)c2 * En];
            T += v;
            run += (c2 < c) ? v : 0.0f;
        }
    }

    __syncthreads();   // vm tile visible

    float prev = 0.0f;
    const size_t base = ((size_t)b * Sn + c * CHUNK) * En + e;

#pragma unroll
    for (int t = 0; t < CHUNK; ++t) {
        const int i = c * CHUNK + t;
        const float cur = bf2f(tile[t * 256 + tid]);
        float num, Z;
        if (i & 1) {
            num = w2 * (run - prev) + w1 * prev + w0 * (T - run);
            Z = (float)(i - 1) * w2 + w1 + (float)(Sn - i) * w0 + 1e-8f;
        } else {
            num = w2 * run + w0 * (T - run);
            Z = (float)i * w2 + (float)(Sn - i) * w0 + 1e-8f;
        }
        opre[base + (size_t)t * En] = f2bf(num / Z);
        run += cur;
        prev = cur;
    }
}

// ---------------------------------------------------------------------------
extern "C" void kernel_launch(void* const* d_in, const int* in_sizes, int n_in,
                              void* d_out, int out_size, void* d_ws, size_t ws_size,
                              hipStream_t stream)
{
    // 0:x 1:attention_mask 2:level_indices 3:Wq 4:bq 5:Wk 6:bk 7:Wv 8:bv 9:hier 10:Wo 11:bo
    const float* x    = (const float*)d_in[0];
    const int*   mask = (const int*)d_in[1];
    const float* Wv   = (const float*)d_in[7];
    const float* bv   = (const float*)d_in[8];
    const float* hier = (const float*)d_in[9];
    const float* Wo   = (const float*)d_in[10];
    const float* bo   = (const float*)d_in[11];
    float* out = (float*)d_out;

    char* ws = (char*)d_ws;
    unsigned short* xb    = (unsigned short*)ws;  ws += (size_t)Mtot * En * 2;   // 8 MB
    unsigned short* Wvb   = (unsigned short*)ws;  ws += (size_t)En * En * 2;     // 2 MB
    unsigned short* Wob   = (unsigned short*)ws;  ws += (size_t)En * En * 2;     // 2 MB
    unsigned short* vmb   = (unsigned short*)ws;  ws += (size_t)Mtot * En * 2;   // 8 MB
    float*          csum  = (float*)ws;           ws += (size_t)GCH * En * 4;    // 512 KB
    unsigned short* opreb = (unsigned short*)ws;  ws += (size_t)Mtot * En * 2;   // 8 MB

    dim3 threads(256);

    // Casts to bf16: x + Wv only (Wo is cast inside combine, pre-gemm2)
    cast2<<<dim3((XN + WN) / 1024), threads, 0, stream>>>(x, Wv, xb, Wvb);

    dim3 gemm_grid(16, 32);   // 512 blocks = 2/CU (XCD-swizzled in-kernel)

    // 1) vm = mask ? (x @ Wv.T + bv) : 0 (bf16) + fused 32-row chunk col sums
    gemm_pipe<true, true, true><<<gemm_grid, threads, 0, stream>>>(xb, Wvb, bv, mask, vmb, csum);
    // 2) Wo cast + LDS-staged weighted combine (inline csum scan) -> opre (bf16)
    combine<<<dim3(En / 256, NCH, Bn), threads, 0, stream>>>(vmb, csum, hier, Wo, Wob, opreb);
    // 3) out = opre @ Wo.T + bo (fp32 out)
    gemm_pipe<false, false, false><<<gemm_grid, threads, 0, stream>>>(opreb, Wob, bo, nullptr, out, nullptr);
}